// Round 1
// baseline (660.522 us; speedup 1.0000x reference)
//
#include <hip/hip_runtime.h>

typedef __attribute__((ext_vector_type(8))) short short8;
typedef __attribute__((ext_vector_type(4))) float floatx4;

// RNE float -> bf16 bits (inputs are finite; no NaN handling needed)
static __device__ __forceinline__ unsigned short f2bf(float x) {
    unsigned int u = __float_as_uint(x);
    u += 0x7fffu + ((u >> 16) & 1u);
    return (unsigned short)(u >> 16);
}

// ---------------- K1: histogram of iid ----------------
__global__ void k_hist(const int* __restrict__ iid, int* __restrict__ counts, int N) {
    int n = blockIdx.x * blockDim.x + threadIdx.x;
    if (n < N) atomicAdd(&counts[iid[n]], 1);
}

// ---------------- K2: count-weighted column sums over feat ----------------
__global__ __launch_bounds__(128) void k_stats(const float* __restrict__ feat,
                                               const int* __restrict__ counts,
                                               float* __restrict__ sum, float* __restrict__ sumsq,
                                               int V) {
    int d = threadIdx.x;                       // 0..127
    int rowsPer = (V + gridDim.x - 1) / gridDim.x;
    int v0 = blockIdx.x * rowsPer;
    int v1 = min(V, v0 + rowsPer);
    float s = 0.f, q = 0.f;
    for (int v = v0; v < v1; ++v) {
        float c = (float)counts[v];            // broadcast read
        if (c != 0.f) {
            float f = feat[(size_t)v * 128 + d];
            s += c * f;
            q += c * f * f;
        }
    }
    atomicAdd(&sum[d], s);
    atomicAdd(&sumsq[d], q);
}

// ---------------- K3: BN affine constants ----------------
__global__ __launch_bounds__(128) void k_affine(const float* __restrict__ sum,
                                                const float* __restrict__ sumsq,
                                                const float* __restrict__ gamma,
                                                const float* __restrict__ beta,
                                                float* __restrict__ scale, float* __restrict__ shift,
                                                float invN) {
    int d = threadIdx.x;
    float mean = sum[d] * invN;
    float var  = sumsq[d] * invN - mean * mean;
    float sc   = gamma[d] * rsqrtf(var + 1e-5f);
    scale[d] = sc;
    shift[d] = beta[d] - mean * sc;
}

// ---------------- K4: fold scale into weights; fused bias ----------------
// wut[h][d] = bf16(scale[d]*W_u[d][h])  (transposed, K-contiguous for MFMA B-frag)
// wvs[d][h] = scale[d]*W_v[d][h]
// cbias[h]  = b_v[h] + sum_d shift[d]*(W_u[d][h]+W_v[d][h])
__global__ __launch_bounds__(128) void k_prep(const float* __restrict__ Wu, const float* __restrict__ Wv,
                                              const float* __restrict__ bv,
                                              const float* __restrict__ scale, const float* __restrict__ shift,
                                              unsigned short* __restrict__ wut, float* __restrict__ wvs,
                                              float* __restrict__ cbias) {
    int h = blockIdx.x, d = threadIdx.x;
    float sc = scale[d], sh = shift[d];
    float wu = Wu[d * 128 + h], wv = Wv[d * 128 + h];
    wut[h * 128 + d] = f2bf(sc * wu);
    wvs[d * 128 + h] = sc * wv;
    __shared__ float red[128];
    red[d] = sh * (wu + wv);
    __syncthreads();
    for (int off = 64; off > 0; off >>= 1) {
        if (d < off) red[d] += red[d + off];
        __syncthreads();
    }
    if (d == 0) cbias[h] = bv[h] + red[0];
}

// ---------------- K5: feat_v per graph (8 graphs / block) ----------------
__global__ __launch_bounds__(128) void k_fv(const float* __restrict__ feat, const int* __restrict__ iid,
                                            const int* __restrict__ last, const float* __restrict__ wvs,
                                            const float* __restrict__ cbias, float* __restrict__ fv,
                                            int B) {
    const int GPB = 8;
    int b0 = blockIdx.x * GPB;
    int h = threadIdx.x;
    __shared__ float sx[GPB][128];
    for (int g = 0; g < GPB; ++g) {
        int b = b0 + g;
        if (b < B) {
            int row = iid[last[b]];
            sx[g][h] = feat[(size_t)row * 128 + h];
        }
    }
    __syncthreads();
    float acc[GPB];
#pragma unroll
    for (int g = 0; g < GPB; ++g) acc[g] = 0.f;
    for (int d = 0; d < 128; ++d) {
        float w = wvs[d * 128 + h];            // coalesced
#pragma unroll
        for (int g = 0; g < GPB; ++g) acc[g] += sx[g][d] * w;  // LDS broadcast
    }
    float c = cbias[h];
    for (int g = 0; g < GPB; ++g)
        if (b0 + g < B) fv[(size_t)(b0 + g) * 128 + h] = acc[g] + c;
}

// ---------------- K6: the big one. e[n] = w_e . sigmoid(feat_raw[iid[n]]@Wu' + fv[seg[n]]) ----
// 64 nodes/block, 4 waves, each wave does a 16x128 tile via 16x16x32 bf16 MFMA.
// W (32KB bf16, transposed) staged to LDS once per block; grid-stride over node tiles.
__global__ __launch_bounds__(256) void k_main(const float* __restrict__ feat, const int* __restrict__ iid,
                                              const int* __restrict__ seg,
                                              const unsigned short* __restrict__ wut,
                                              const float* __restrict__ fv, const float* __restrict__ we_g,
                                              float* __restrict__ e_out, int N, int numTiles) {
    __shared__ unsigned short sW[128][136];    // [h][k], +8 pad breaks 16-way bank aliasing
    __shared__ unsigned short sA[64][136];     // [node][k]

    int tid = threadIdx.x;
    // stage W once: thread -> row tid>>1, half (tid&1)*64 ushorts = 8x uint4
    {
        int r = tid >> 1, half = tid & 1;
        const uint4* src = (const uint4*)(wut + r * 128 + half * 64);
        uint4* dst = (uint4*)&sW[r][half * 64];
#pragma unroll
        for (int i = 0; i < 8; ++i) dst[i] = src[i];
    }

    int wv = tid >> 6;          // wave 0..3
    int lane = tid & 63;
    int q = lane >> 4, c = lane & 15;
    int m0 = wv * 16;

    float we[8];
#pragma unroll
    for (int t = 0; t < 8; ++t) we[t] = we_g[t * 16 + c];

    for (int tile = blockIdx.x; tile < numTiles; tile += gridDim.x) {
        int n0 = tile * 64;
        __syncthreads();       // sA reuse guard (also covers initial W staging)
        // stage A: thread -> node tid>>2, quarter (tid&3)*32 floats -> bf16
        {
            int r = tid >> 2, p = tid & 3;
            int n = n0 + r;
            int row = (n < N) ? iid[n] : 0;
            const float4* src = (const float4*)(feat + (size_t)row * 128 + p * 32);
            ushort4* dst = (ushort4*)&sA[r][p * 32];
#pragma unroll
            for (int i = 0; i < 8; ++i) {
                float4 f = src[i];
                ushort4 u;
                u.x = f2bf(f.x); u.y = f2bf(f.y); u.z = f2bf(f.z); u.w = f2bf(f.w);
                dst[i] = u;
            }
        }
        __syncthreads();

        floatx4 acc[8];
#pragma unroll
        for (int t = 0; t < 8; ++t) acc[t] = (floatx4)(0.f);
#pragma unroll
        for (int kc = 0; kc < 4; ++kc) {
            short8 a = *(const short8*)&sA[m0 + c][kc * 32 + q * 8];
#pragma unroll
            for (int t = 0; t < 8; ++t) {
                short8 b = *(const short8*)&sW[t * 16 + c][kc * 32 + q * 8];
                acc[t] = __builtin_amdgcn_mfma_f32_16x16x32_bf16(a, b, acc[t], 0, 0, 0);
            }
        }

        // epilogue: lane holds u[node = m0+q*4+r][h = t*16+c] in acc[t][r]
#pragma unroll
        for (int r = 0; r < 4; ++r) {
            int n = n0 + m0 + q * 4 + r;
            float p = 0.f;
            if (n < N) {
                int sg = seg[n];
                const float* fvp = fv + (size_t)sg * 128;
#pragma unroll
                for (int t = 0; t < 8; ++t) {
                    float u = acc[t][r] + fvp[t * 16 + c];
                    p += we[t] / (1.f + __expf(-u));
                }
            }
            p += __shfl_xor(p, 1);
            p += __shfl_xor(p, 2);
            p += __shfl_xor(p, 4);
            p += __shfl_xor(p, 8);
            if (c == 0 && n < N) e_out[n] = p;
        }
    }
}

// ---------------- K7: segment boundaries (segment_ids sorted) ----------------
__global__ void k_bounds(const int* __restrict__ seg, int* __restrict__ start, int N, int B) {
    int n = blockIdx.x * blockDim.x + threadIdx.x;
    if (n >= N) return;
    int cur = seg[n];
    int prev = (n == 0) ? -1 : seg[n - 1];
    for (int b = prev + 1; b <= cur; ++b) start[b] = n;
    if (n == N - 1)
        for (int b = cur + 1; b <= B; ++b) start[b] = N;
}

// ---------------- K8: per-segment softmax + weighted raw-feature sum ----------------
// rst[b][d] = scale[d]*sum_n alpha_n*feat_raw[n][d] + shift[d]*(len>0)
__global__ __launch_bounds__(128) void k_rst(const float* __restrict__ feat, const int* __restrict__ iid,
                                             const float* __restrict__ e, const int* __restrict__ start,
                                             const float* __restrict__ scale, const float* __restrict__ shift,
                                             float* __restrict__ rst) {
    int b = blockIdx.x;
    int d = threadIdx.x;
    int s = start[b], t = start[b + 1];
    __shared__ float red[128];
    float mx = -3.4e38f;
    for (int n = s + d; n < t; n += 128) mx = fmaxf(mx, e[n]);
    red[d] = mx; __syncthreads();
    for (int off = 64; off > 0; off >>= 1) {
        if (d < off) red[d] = fmaxf(red[d], red[d + off]);
        __syncthreads();
    }
    mx = red[0]; __syncthreads();
    float sm = 0.f;
    for (int n = s + d; n < t; n += 128) sm += __expf(e[n] - mx);
    red[d] = sm; __syncthreads();
    for (int off = 64; off > 0; off >>= 1) {
        if (d < off) red[d] += red[d + off];
        __syncthreads();
    }
    float inv = (t > s) ? 1.f / red[0] : 0.f;
    float acc = 0.f;
    for (int n = s; n < t; ++n) {
        float a = __expf(e[n] - mx) * inv;            // broadcast reads, redundant exp (cheap)
        acc += a * feat[(size_t)iid[n] * 128 + d];    // coalesced 512B row
    }
    float asum = (t > s) ? 1.f : 0.f;
    rst[(size_t)b * 128 + d] = scale[d] * acc + shift[d] * asum;
}

// ---------------- K9: out = rst @ W_out  [B,128]x[128,256] ----------------
__global__ __launch_bounds__(256) void k_out(const float* __restrict__ rst, const float* __restrict__ Wout,
                                             float* __restrict__ out, int B) {
    __shared__ float sT[128][36];  // transposed rst tile, padded (row start 144B -> 16B aligned)
    int b0 = blockIdx.x * 32;
    int t = threadIdx.x;
    for (int i = 0; i < 16; ++i) {
        int idx = i * 256 + t;
        int r = idx >> 7, d = idx & 127;
        int b = min(b0 + r, B - 1);
        sT[d][r] = rst[(size_t)b * 128 + d];
    }
    __syncthreads();
    float acc[32];
#pragma unroll
    for (int r = 0; r < 32; ++r) acc[r] = 0.f;
    for (int dd = 0; dd < 128; ++dd) {
        float w = Wout[dd * 256 + t];                  // coalesced
        const float4* row = (const float4*)&sT[dd][0]; // broadcast LDS reads
#pragma unroll
        for (int r4 = 0; r4 < 8; ++r4) {
            float4 v = row[r4];
            acc[r4 * 4 + 0] += w * v.x;
            acc[r4 * 4 + 1] += w * v.y;
            acc[r4 * 4 + 2] += w * v.z;
            acc[r4 * 4 + 3] += w * v.w;
        }
    }
    for (int r = 0; r < 32; ++r)
        if (b0 + r < B) out[(size_t)(b0 + r) * 256 + t] = acc[r];
}

extern "C" void kernel_launch(void* const* d_in, const int* in_sizes, int n_in,
                              void* d_out, int out_size, void* d_ws, size_t ws_size,
                              hipStream_t stream) {
    const float* feat  = (const float*)d_in[0];
    const int*   iid   = (const int*)d_in[1];
    const int*   seg   = (const int*)d_in[2];
    const int*   last  = (const int*)d_in[3];
    const float* gamma = (const float*)d_in[4];
    const float* beta  = (const float*)d_in[5];
    const float* Wu    = (const float*)d_in[6];
    const float* Wv    = (const float*)d_in[7];
    const float* bv    = (const float*)d_in[8];
    const float* we    = (const float*)d_in[9];
    const float* Wout  = (const float*)d_in[10];
    float* out = (float*)d_out;

    int V = in_sizes[0] / 128;
    int N = in_sizes[1];
    int B = in_sizes[3];

    // workspace carve-up (256B aligned)
    char* w = (char*)d_ws;
    size_t off = 0;
    auto alloc = [&](size_t bytes) -> void* {
        void* p = w + off;
        off += (bytes + 255) & ~(size_t)255;
        return p;
    };
    int*   counts = (int*)alloc((size_t)V * 4);
    float* dsum   = (float*)alloc(512);
    float* dsumsq = (float*)alloc(512);
    size_t zero_bytes = off;                 // memset counts+sums
    float* scale  = (float*)alloc(512);
    float* shift  = (float*)alloc(512);
    float* cbias  = (float*)alloc(512);
    unsigned short* wut = (unsigned short*)alloc(128 * 128 * 2);
    float* wvs    = (float*)alloc(128 * 128 * 4);
    float* fv     = (float*)alloc((size_t)B * 128 * 4);
    float* e      = (float*)alloc((size_t)N * 4);
    int*   startA = (int*)alloc((size_t)(B + 1) * 4);
    float* rst    = (float*)alloc((size_t)B * 128 * 4);
    (void)ws_size; (void)n_in; (void)out_size;

    hipMemsetAsync(d_ws, 0, zero_bytes, stream);

    k_hist<<<(N + 255) / 256, 256, 0, stream>>>(iid, counts, N);
    k_stats<<<256, 128, 0, stream>>>(feat, counts, dsum, dsumsq, V);
    k_affine<<<1, 128, 0, stream>>>(dsum, dsumsq, gamma, beta, scale, shift, 1.0f / (float)N);
    k_prep<<<128, 128, 0, stream>>>(Wu, Wv, bv, scale, shift, wut, wvs, cbias);
    k_fv<<<(B + 7) / 8, 128, 0, stream>>>(feat, iid, last, wvs, cbias, fv, B);

    int numTiles = (N + 63) / 64;
    k_main<<<2048, 256, 0, stream>>>(feat, iid, seg, wut, fv, we, e, N, numTiles);

    k_bounds<<<(N + 255) / 256, 256, 0, stream>>>(seg, startA, N, B);
    k_rst<<<B, 128, 0, stream>>>(feat, iid, e, startA, scale, shift, rst);
    k_out<<<(B + 31) / 32, 256, 0, stream>>>(rst, Wout, out, B);
}

// Round 2
// 577.851 us; speedup vs baseline: 1.1431x; 1.1431x over previous
//
#include <hip/hip_runtime.h>

typedef __attribute__((ext_vector_type(8))) short short8;
typedef __attribute__((ext_vector_type(4))) float floatx4;

// RNE float -> bf16 bits (inputs finite)
static __device__ __forceinline__ unsigned short f2bf(float x) {
    unsigned int u = __float_as_uint(x);
    u += 0x7fffu + ((u >> 16) & 1u);
    return (unsigned short)(u >> 16);
}
static __device__ __forceinline__ float bf2f(unsigned short h) {
    return __uint_as_float(((unsigned int)h) << 16);
}

// ---------------- K0: feat fp32 -> bf16 table ----------------
__global__ __launch_bounds__(256) void k_cvt(const float* __restrict__ feat,
                                             unsigned int* __restrict__ featb2,  // packed 2xbf16
                                             int total8) {                       // groups of 8 floats
    int i = blockIdx.x * blockDim.x + threadIdx.x;
    if (i >= total8) return;
    const float4* src = (const float4*)feat + (size_t)i * 2;
    float4 f0 = src[0], f1 = src[1];
    uint4 o;
    o.x = (unsigned)f2bf(f0.x) | ((unsigned)f2bf(f0.y) << 16);
    o.y = (unsigned)f2bf(f0.z) | ((unsigned)f2bf(f0.w) << 16);
    o.z = (unsigned)f2bf(f1.x) | ((unsigned)f2bf(f1.y) << 16);
    o.w = (unsigned)f2bf(f1.z) | ((unsigned)f2bf(f1.w) << 16);
    ((uint4*)featb2)[i] = o;
}

// ---------------- K1: histogram of iid ----------------
__global__ void k_hist(const int* __restrict__ iid, int* __restrict__ counts, int N) {
    int n = blockIdx.x * blockDim.x + threadIdx.x;
    if (n < N) atomicAdd(&counts[iid[n]], 1);
}

// ---------------- K2: count-weighted column sums over feat ----------------
__global__ __launch_bounds__(128) void k_stats(const float* __restrict__ feat,
                                               const int* __restrict__ counts,
                                               float* __restrict__ sum, float* __restrict__ sumsq,
                                               int V) {
    int d = threadIdx.x;
    int rowsPer = (V + gridDim.x - 1) / gridDim.x;
    int v0 = blockIdx.x * rowsPer;
    int v1 = min(V, v0 + rowsPer);
    float s = 0.f, q = 0.f;
    for (int v = v0; v < v1; ++v) {
        float c = (float)counts[v];
        if (c != 0.f) {
            float f = feat[(size_t)v * 128 + d];
            s += c * f;
            q += c * f * f;
        }
    }
    atomicAdd(&sum[d], s);
    atomicAdd(&sumsq[d], q);
}

// ---------------- K3: BN affine constants ----------------
__global__ __launch_bounds__(128) void k_affine(const float* __restrict__ sum,
                                                const float* __restrict__ sumsq,
                                                const float* __restrict__ gamma,
                                                const float* __restrict__ beta,
                                                float* __restrict__ scale, float* __restrict__ shift,
                                                float invN) {
    int d = threadIdx.x;
    float mean = sum[d] * invN;
    float var  = sumsq[d] * invN - mean * mean;
    float sc   = gamma[d] * rsqrtf(var + 1e-5f);
    scale[d] = sc;
    shift[d] = beta[d] - mean * sc;
}

// ---------------- K4: fold scale into weights; fused bias ----------------
__global__ __launch_bounds__(128) void k_prep(const float* __restrict__ Wu, const float* __restrict__ Wv,
                                              const float* __restrict__ bv,
                                              const float* __restrict__ scale, const float* __restrict__ shift,
                                              unsigned short* __restrict__ wut, float* __restrict__ wvs,
                                              float* __restrict__ cbias) {
    int h = blockIdx.x, d = threadIdx.x;
    float sc = scale[d], sh = shift[d];
    float wu = Wu[d * 128 + h], wv = Wv[d * 128 + h];
    wut[h * 128 + d] = f2bf(sc * wu);
    wvs[d * 128 + h] = sc * wv;
    __shared__ float red[128];
    red[d] = sh * (wu + wv);
    __syncthreads();
    for (int off = 64; off > 0; off >>= 1) {
        if (d < off) red[d] += red[d + off];
        __syncthreads();
    }
    if (d == 0) cbias[h] = bv[h] + red[0];
}

// ---------------- K5: feat_v per graph ----------------
__global__ __launch_bounds__(128) void k_fv(const float* __restrict__ feat, const int* __restrict__ iid,
                                            const int* __restrict__ last, const float* __restrict__ wvs,
                                            const float* __restrict__ cbias, float* __restrict__ fv,
                                            int B) {
    const int GPB = 8;
    int b0 = blockIdx.x * GPB;
    int h = threadIdx.x;
    __shared__ float sx[GPB][128];
    for (int g = 0; g < GPB; ++g) {
        int b = b0 + g;
        if (b < B) {
            int row = iid[last[b]];
            sx[g][h] = feat[(size_t)row * 128 + h];
        }
    }
    __syncthreads();
    float acc[GPB];
#pragma unroll
    for (int g = 0; g < GPB; ++g) acc[g] = 0.f;
    for (int d = 0; d < 128; ++d) {
        float w = wvs[d * 128 + h];
#pragma unroll
        for (int g = 0; g < GPB; ++g) acc[g] += sx[g][d] * w;
    }
    float c = cbias[h];
    for (int g = 0; g < GPB; ++g)
        if (b0 + g < B) fv[(size_t)(b0 + g) * 128 + h] = acc[g] + c;
}

// ---------------- K6: fused main ----------------
// Per 64-node tile: u = bf16(feat[iid]) @ Wu' (MFMA, waves partition H, W in regs),
// e = w_e . sigmoid(u + fv[seg]); ex = exp(e); denom[seg] += ex;
// rst_un[seg][:] += ex * row  (in-LDS segmented reduction, coalesced atomics).
__global__ __launch_bounds__(256, 4) void k_main(
        const unsigned short* __restrict__ featb, const int* __restrict__ iid,
        const int* __restrict__ seg, const unsigned short* __restrict__ wut,
        const float* __restrict__ fv, const float* __restrict__ we_g,
        float* __restrict__ denom, float* __restrict__ rstu,
        int N, int numTiles) {
    __shared__ unsigned short sA[64][136];   // bf16 rows, +8 pad
    __shared__ int   sSeg[64];
    __shared__ float sEx[64];
    __shared__ float sEpart[4][64];
    __shared__ float sFv[8][128];

    int tid = threadIdx.x;
    int wv = tid >> 6, lane = tid & 63, q = lane >> 4, c = lane & 15;

    // one-time: this wave's B fragments (2 h-tiles x 4 k-chunks) from global
    short8 bf[2][4];
    float we2[2];
#pragma unroll
    for (int t = 0; t < 2; ++t) {
        int h = (2 * wv + t) * 16 + c;
        we2[t] = we_g[h];
#pragma unroll
        for (int kc = 0; kc < 4; ++kc)
            bf[t][kc] = *(const short8*)(wut + h * 128 + kc * 32 + q * 8);
    }

    for (int tile = blockIdx.x; tile < numTiles; tile += gridDim.x) {
        int n0 = tile << 6;
        __syncthreads();                       // B1: prev tile stage-3 done with sA/sSeg/sEx
        // stage A rows (bf16) + seg ids
        {
            int r = tid >> 2, p = tid & 3;
            int n = n0 + r;
            int nn = (n < N) ? n : (N - 1);
            int row = iid[nn];
            const uint4* src = (const uint4*)(featb + (size_t)row * 128 + p * 32);
            uint4 v0 = src[0], v1 = src[1], v2 = src[2], v3 = src[3];
            uint4* dst = (uint4*)&sA[r][p * 32];
            dst[0] = v0; dst[1] = v1; dst[2] = v2; dst[3] = v3;
            if (tid < 64) {
                int m = n0 + tid;
                sSeg[tid] = seg[(m < N) ? m : (N - 1)];
            }
        }
        __syncthreads();                       // B2
        // cache fv rows for this tile's segment range (usually 2-3 rows)
        int s0 = sSeg[0];
        int range = sSeg[63] - s0 + 1;
        bool fvLds = (range <= 8);
        if (fvLds) {
            for (int idx = tid; idx < (range << 7); idx += 256)
                sFv[0][idx] = fv[((size_t)s0 << 7) + idx];
        }
        // MFMA: acc[mt][t] : nodes mt*16.., h-tile 2wv+t
        floatx4 acc[4][2];
#pragma unroll
        for (int mt = 0; mt < 4; ++mt)
#pragma unroll
            for (int t = 0; t < 2; ++t) acc[mt][t] = (floatx4)(0.f);
#pragma unroll
        for (int kc = 0; kc < 4; ++kc) {
            short8 a0 = *(const short8*)&sA[ 0 + c][kc * 32 + q * 8];
            short8 a1 = *(const short8*)&sA[16 + c][kc * 32 + q * 8];
            short8 a2 = *(const short8*)&sA[32 + c][kc * 32 + q * 8];
            short8 a3 = *(const short8*)&sA[48 + c][kc * 32 + q * 8];
#pragma unroll
            for (int t = 0; t < 2; ++t) {
                acc[0][t] = __builtin_amdgcn_mfma_f32_16x16x32_bf16(a0, bf[t][kc], acc[0][t], 0, 0, 0);
                acc[1][t] = __builtin_amdgcn_mfma_f32_16x16x32_bf16(a1, bf[t][kc], acc[1][t], 0, 0, 0);
                acc[2][t] = __builtin_amdgcn_mfma_f32_16x16x32_bf16(a2, bf[t][kc], acc[2][t], 0, 0, 0);
                acc[3][t] = __builtin_amdgcn_mfma_f32_16x16x32_bf16(a3, bf[t][kc], acc[3][t], 0, 0, 0);
            }
        }
        __syncthreads();                       // B3: sFv ready (and sEpart free)
        // partial e over this wave's 32 h-columns
#pragma unroll
        for (int mt = 0; mt < 4; ++mt)
#pragma unroll
            for (int r = 0; r < 4; ++r) {
                int nl = mt * 16 + q * 4 + r;
                int sg = sSeg[nl];
                float f0, f1;
                int h0 = (2 * wv) * 16 + c, h1 = h0 + 16;
                if (fvLds) {
                    f0 = sFv[sg - s0][h0];
                    f1 = sFv[sg - s0][h1];
                } else {
                    f0 = fv[((size_t)sg << 7) + h0];
                    f1 = fv[((size_t)sg << 7) + h1];
                }
                float u0 = acc[mt][0][r] + f0;
                float u1 = acc[mt][1][r] + f1;
                float p = we2[0] / (1.f + __expf(-u0)) + we2[1] / (1.f + __expf(-u1));
                p += __shfl_xor(p, 1);
                p += __shfl_xor(p, 2);
                p += __shfl_xor(p, 4);
                p += __shfl_xor(p, 8);
                if (c == 0) sEpart[wv][nl] = p;
            }
        __syncthreads();                       // B4
        if (tid < 64) {
            float s = sEpart[0][tid] + sEpart[1][tid] + sEpart[2][tid] + sEpart[3][tid];
            float ex = 0.f;
            if (n0 + tid < N) {
                ex = __expf(s);                // no max-shift needed: |e| <= ~11.3
                atomicAdd(&denom[sSeg[tid]], ex);
            }
            sEx[tid] = ex;
        }
        __syncthreads();                       // B5
        // segmented weighted row-sum: rst_un[seg][d] += ex * A[row][d]
        {
            int d = tid & 127, h2 = tid >> 7;
            int j0 = h2 << 5;
            float a = 0.f;
            int cur = sSeg[j0];
#pragma unroll 4
            for (int j = j0; j < j0 + 32; ++j) {
                int s = sSeg[j];
                if (s != cur) {
                    atomicAdd(&rstu[((size_t)cur << 7) + d], a);
                    a = 0.f; cur = s;
                }
                a += sEx[j] * bf2f(sA[j][d]);
            }
            atomicAdd(&rstu[((size_t)cur << 7) + d], a);
        }
    }
}

// ---------------- K7: out = (scale*rst_un/denom + shift*(denom>0)) @ W_out ----------------
__global__ __launch_bounds__(256) void k_out(const float* __restrict__ rstu, const float* __restrict__ denomA,
                                             const float* __restrict__ scale, const float* __restrict__ shift,
                                             const float* __restrict__ Wout, float* __restrict__ out, int B) {
    __shared__ float sT[128][36];
    int b0 = blockIdx.x * 32;
    int t = threadIdx.x;
    for (int i = 0; i < 16; ++i) {
        int idx = i * 256 + t;
        int r = idx >> 7, d = idx & 127;
        int b = min(b0 + r, B - 1);
        float dn = denomA[b];
        float inv = (dn > 0.f) ? 1.f / dn : 0.f;
        float msk = (dn > 0.f) ? 1.f : 0.f;
        sT[d][r] = rstu[((size_t)b << 7) + d] * scale[d] * inv + shift[d] * msk;
    }
    __syncthreads();
    float acc[32];
#pragma unroll
    for (int r = 0; r < 32; ++r) acc[r] = 0.f;
    for (int dd = 0; dd < 128; ++dd) {
        float w = Wout[dd * 256 + t];
        const float4* row = (const float4*)&sT[dd][0];
#pragma unroll
        for (int r4 = 0; r4 < 8; ++r4) {
            float4 v = row[r4];
            acc[r4 * 4 + 0] += w * v.x;
            acc[r4 * 4 + 1] += w * v.y;
            acc[r4 * 4 + 2] += w * v.z;
            acc[r4 * 4 + 3] += w * v.w;
        }
    }
    for (int r = 0; r < 32; ++r)
        if (b0 + r < B) out[(size_t)(b0 + r) * 256 + t] = acc[r];
}

extern "C" void kernel_launch(void* const* d_in, const int* in_sizes, int n_in,
                              void* d_out, int out_size, void* d_ws, size_t ws_size,
                              hipStream_t stream) {
    const float* feat  = (const float*)d_in[0];
    const int*   iid   = (const int*)d_in[1];
    const int*   seg   = (const int*)d_in[2];
    const int*   last  = (const int*)d_in[3];
    const float* gamma = (const float*)d_in[4];
    const float* beta  = (const float*)d_in[5];
    const float* Wu    = (const float*)d_in[6];
    const float* Wv    = (const float*)d_in[7];
    const float* bv    = (const float*)d_in[8];
    const float* we    = (const float*)d_in[9];
    const float* Wout  = (const float*)d_in[10];
    float* out = (float*)d_out;

    int V = in_sizes[0] / 128;
    int N = in_sizes[1];
    int B = in_sizes[3];

    char* w = (char*)d_ws;
    size_t off = 0;
    auto alloc = [&](size_t bytes) -> void* {
        void* p = w + off;
        off += (bytes + 255) & ~(size_t)255;
        return p;
    };
    // zero-init region first
    int*   counts = (int*)alloc((size_t)V * 4);
    float* dsum   = (float*)alloc(512);
    float* dsumsq = (float*)alloc(512);
    float* denom  = (float*)alloc((size_t)B * 4);
    float* rstu   = (float*)alloc((size_t)B * 128 * 4);
    size_t zero_bytes = off;
    // rest
    float* scale  = (float*)alloc(512);
    float* shift  = (float*)alloc(512);
    float* cbias  = (float*)alloc(512);
    unsigned short* wut = (unsigned short*)alloc(128 * 128 * 2);
    float* wvs    = (float*)alloc(128 * 128 * 4);
    float* fv     = (float*)alloc((size_t)B * 128 * 4);
    unsigned short* featb = (unsigned short*)alloc((size_t)V * 128 * 2);
    (void)ws_size; (void)n_in; (void)out_size;

    hipMemsetAsync(d_ws, 0, zero_bytes, stream);

    int total8 = V * 128 / 8;
    k_cvt<<<(total8 + 255) / 256, 256, 0, stream>>>(feat, (unsigned int*)featb, total8);
    k_hist<<<(N + 255) / 256, 256, 0, stream>>>(iid, counts, N);
    k_stats<<<1024, 128, 0, stream>>>(feat, counts, dsum, dsumsq, V);
    k_affine<<<1, 128, 0, stream>>>(dsum, dsumsq, gamma, beta, scale, shift, 1.0f / (float)N);
    k_prep<<<128, 128, 0, stream>>>(Wu, Wv, bv, scale, shift, wut, wvs, cbias);
    k_fv<<<(B + 7) / 8, 128, 0, stream>>>(feat, iid, last, wvs, cbias, fv, B);

    int numTiles = (N + 63) / 64;
    k_main<<<2048, 256, 0, stream>>>(featb, iid, seg, wut, fv, we, denom, rstu, N, numTiles);

    k_out<<<(B + 31) / 32, 256, 0, stream>>>(rstu, denom, scale, shift, Wout, out, B);
}

// Round 3
// 416.639 us; speedup vs baseline: 1.5854x; 1.3869x over previous
//
#include <hip/hip_runtime.h>

typedef __attribute__((ext_vector_type(8))) short short8;
typedef __attribute__((ext_vector_type(4))) float floatx4;

static __device__ __forceinline__ unsigned short f2bf(float x) {
    unsigned int u = __float_as_uint(x);
    u += 0x7fffu + ((u >> 16) & 1u);
    return (unsigned short)(u >> 16);
}

// ---------------- K1: histogram of iid ----------------
__global__ void k_hist(const int* __restrict__ iid, int* __restrict__ counts, int N) {
    int n = blockIdx.x * blockDim.x + threadIdx.x;
    if (n < N) atomicAdd(&counts[iid[n]], 1);
}

// ---------------- K2: fp32->bf16 convert + count-weighted stats (one feat pass) ------
__global__ __launch_bounds__(256) void k_cvtstats(const float* __restrict__ feat,
                                                  const int* __restrict__ counts,
                                                  unsigned short* __restrict__ featb,
                                                  float* __restrict__ dsum, float* __restrict__ dsumsq,
                                                  int V) {
    int tid = threadIdx.x;
    int r2 = tid >> 7, d = tid & 127;
    float s = 0.f, qa = 0.f;
    for (int vp = blockIdx.x; vp * 2 < V; vp += gridDim.x) {
        int v = vp * 2 + r2;
        if (v >= V) continue;
        float f = feat[(size_t)v * 128 + d];
        featb[(size_t)v * 128 + d] = f2bf(f);
        float c = (float)counts[v];
        if (c != 0.f) { s += c * f; qa += c * f * f; }
    }
    __shared__ float red[256];
    red[tid] = s; __syncthreads();
    if (tid < 128) atomicAdd(&dsum[d], red[tid] + red[tid + 128]);
    __syncthreads();
    red[tid] = qa; __syncthreads();
    if (tid < 128) atomicAdd(&dsumsq[d], red[tid] + red[tid + 128]);
}

// ---------------- K3: BN affine constants ----------------
__global__ __launch_bounds__(128) void k_affine(const float* __restrict__ sum,
                                                const float* __restrict__ sumsq,
                                                const float* __restrict__ gamma,
                                                const float* __restrict__ beta,
                                                float* __restrict__ scale, float* __restrict__ shift,
                                                float invN) {
    int d = threadIdx.x;
    float mean = sum[d] * invN;
    float var  = sumsq[d] * invN - mean * mean;
    float sc   = gamma[d] * rsqrtf(var + 1e-5f);
    scale[d] = sc;
    shift[d] = beta[d] - mean * sc;
}

// ---------------- K4: fold scale into weights; fused bias ----------------
__global__ __launch_bounds__(128) void k_prep(const float* __restrict__ Wu, const float* __restrict__ Wv,
                                              const float* __restrict__ bv,
                                              const float* __restrict__ scale, const float* __restrict__ shift,
                                              unsigned short* __restrict__ wut, float* __restrict__ wvs,
                                              float* __restrict__ cbias) {
    int h = blockIdx.x, d = threadIdx.x;
    float sc = scale[d], sh = shift[d];
    float wu = Wu[d * 128 + h], wv = Wv[d * 128 + h];
    wut[h * 128 + d] = f2bf(sc * wu);
    wvs[d * 128 + h] = sc * wv;
    __shared__ float red[128];
    red[d] = sh * (wu + wv);
    __syncthreads();
    for (int off = 64; off > 0; off >>= 1) {
        if (d < off) red[d] += red[d + off];
        __syncthreads();
    }
    if (d == 0) cbias[h] = bv[h] + red[0];
}

// ---------------- K5: feat_v per graph ----------------
__global__ __launch_bounds__(128) void k_fv(const float* __restrict__ feat, const int* __restrict__ iid,
                                            const int* __restrict__ last, const float* __restrict__ wvs,
                                            const float* __restrict__ cbias, float* __restrict__ fv,
                                            int B) {
    const int GPB = 8;
    int b0 = blockIdx.x * GPB;
    int h = threadIdx.x;
    __shared__ float sx[GPB][128];
    for (int g = 0; g < GPB; ++g) {
        int b = b0 + g;
        if (b < B) {
            int row = iid[last[b]];
            sx[g][h] = feat[(size_t)row * 128 + h];
        }
    }
    __syncthreads();
    float acc[GPB];
#pragma unroll
    for (int g = 0; g < GPB; ++g) acc[g] = 0.f;
    for (int d = 0; d < 128; ++d) {
        float w = wvs[d * 128 + h];
#pragma unroll
        for (int g = 0; g < GPB; ++g) acc[g] += sx[g][d] * w;
    }
    float c = cbias[h];
    for (int g = 0; g < GPB; ++g)
        if (b0 + g < B) fv[(size_t)(b0 + g) * 128 + h] = acc[g] + c;
}

// ---------------- K6: pipelined e-kernel ----------------
// ex[n] = exp( w_e . sigmoid(bf16(feat[iid[n]]) @ Wu' + fv[seg[n]]) )
// One barrier per 64-node tile; global_load_lds prefetch of tile t+1 (XOR-swizzled
// 16B chunks so unpadded ds_read_b128 stays ~2-way); iid/seg/fv prefetched depth-2.
__global__ __launch_bounds__(256, 3) void k_main(
        const unsigned short* __restrict__ featb, const int* __restrict__ iid,
        const int* __restrict__ seg, const unsigned short* __restrict__ wut,
        const float* __restrict__ fv, const float* __restrict__ we_g,
        float* __restrict__ exo, int N, int B, int numTiles) {
    __shared__ unsigned short sA[2][64 * 128];
    __shared__ int   sSeg[2][64];
    __shared__ float sFv[2][4][128];
    __shared__ float sEp[2][4][64];

    int tid = threadIdx.x;
    int wv = tid >> 6, lane = tid & 63, q = lane >> 4, c = lane & 15;
    int p2 = lane & 15;
    int rowbase = wv * 16 + (lane >> 4);

    // one-time B fragments in registers (2 h-tiles per wave)
    short8 bfr[2][4];
    float we2[2];
#pragma unroll
    for (int t = 0; t < 2; ++t) {
        int h = (2 * wv + t) * 16 + c;
        we2[t] = we_g[h];
#pragma unroll
        for (int kc = 0; kc < 4; ++kc)
            bfr[t][kc] = *(const short8*)(wut + h * 128 + kc * 32 + q * 8);
    }

    if (blockIdx.x >= numTiles) return;

    int iidR[4]; int segR; float2 fvR;
    auto loadRegs = [&](int T) {
        int n0 = T << 6;
#pragma unroll
        for (int k = 0; k < 4; ++k)
            iidR[k] = iid[min(n0 + rowbase + 4 * k, N - 1)];
        segR = seg[min(n0 + (tid & 63), N - 1)];
        int s0 = seg[min(n0, N - 1)];
        int fvrow = min(s0 + (tid >> 6), B - 1);
        fvR = *(const float2*)(fv + (size_t)fvrow * 128 + ((tid << 1) & 127));
    };
    auto stage = [&](int buf) {
        unsigned short* sAb = &sA[buf][0];
#pragma unroll
        for (int k = 0; k < 4; ++k) {
            int row = rowbase + 4 * k;
            int j = (p2 & 8) | ((p2 & 7) ^ (row & 7));
            const unsigned short* g = featb + (size_t)iidR[k] * 128 + j * 8;
            __builtin_amdgcn_global_load_lds(
                (const __attribute__((address_space(1))) void*)g,
                (__attribute__((address_space(3))) void*)(sAb + wv * 2048 + k * 512),
                16, 0, 0);
        }
        if (tid < 64) sSeg[buf][tid] = segR;
        *(float2*)&sFv[buf][tid >> 6][(tid << 1) & 127] = fvR;
    };

    int T = blockIdx.x;
    loadRegs(T);
    stage(0);
    int prevN0 = -1;
    int cur = 0;

    for (;;) {
        int Tn = T + gridDim.x;
        bool hn = (Tn < numTiles);
        if (hn) loadRegs(Tn);
        __syncthreads();            // buf[cur] loads complete; buf[cur^1] readers done
        if (hn) stage(cur ^ 1);

        // ---- compute tile T from buf[cur] ----
        floatx4 acc[4][2];
#pragma unroll
        for (int mt = 0; mt < 4; ++mt)
#pragma unroll
            for (int t = 0; t < 2; ++t) acc[mt][t] = (floatx4)(0.f);
#pragma unroll
        for (int kc = 0; kc < 4; ++kc) {
            int jj = 4 * kc + q;
            int pofs = ((jj & 8) | ((jj & 7) ^ (c & 7))) * 8;
            short8 a0 = *(const short8*)&sA[cur][( 0 + c) * 128 + pofs];
            short8 a1 = *(const short8*)&sA[cur][(16 + c) * 128 + pofs];
            short8 a2 = *(const short8*)&sA[cur][(32 + c) * 128 + pofs];
            short8 a3 = *(const short8*)&sA[cur][(48 + c) * 128 + pofs];
#pragma unroll
            for (int t = 0; t < 2; ++t) {
                acc[0][t] = __builtin_amdgcn_mfma_f32_16x16x32_bf16(a0, bfr[t][kc], acc[0][t], 0, 0, 0);
                acc[1][t] = __builtin_amdgcn_mfma_f32_16x16x32_bf16(a1, bfr[t][kc], acc[1][t], 0, 0, 0);
                acc[2][t] = __builtin_amdgcn_mfma_f32_16x16x32_bf16(a2, bfr[t][kc], acc[2][t], 0, 0, 0);
                acc[3][t] = __builtin_amdgcn_mfma_f32_16x16x32_bf16(a3, bfr[t][kc], acc[3][t], 0, 0, 0);
            }
        }
        // epilogue: partial e over this wave's 32 h-columns
        {
            int s0 = sSeg[cur][0];
            int h0 = wv * 32 + c;
#pragma unroll
            for (int mt = 0; mt < 4; ++mt)
#pragma unroll
                for (int r = 0; r < 4; ++r) {
                    int nl = mt * 16 + q * 4 + r;
                    int sg = sSeg[cur][nl];
                    int off = sg - s0;
                    float f0, f1;
                    if (off < 4) {
                        f0 = sFv[cur][off][h0];
                        f1 = sFv[cur][off][h0 + 16];
                    } else {
                        f0 = fv[((size_t)sg << 7) + h0];
                        f1 = fv[((size_t)sg << 7) + h0 + 16];
                    }
                    float u0 = acc[mt][0][r] + f0;
                    float u1 = acc[mt][1][r] + f1;
                    float p = we2[0] * __builtin_amdgcn_rcpf(1.f + __expf(-u0))
                            + we2[1] * __builtin_amdgcn_rcpf(1.f + __expf(-u1));
                    p += __shfl_xor(p, 1);
                    p += __shfl_xor(p, 2);
                    p += __shfl_xor(p, 4);
                    p += __shfl_xor(p, 8);
                    if (c == 0) sEp[cur][wv][nl] = p;
                }
        }
        // reduce+store previous tile's e (sEp[cur^1], safe: written before last barrier)
        if (prevN0 >= 0 && tid < 64) {
            int n = prevN0 + tid;
            if (n < N) {
                float s = sEp[cur ^ 1][0][tid] + sEp[cur ^ 1][1][tid]
                        + sEp[cur ^ 1][2][tid] + sEp[cur ^ 1][3][tid];
                exo[n] = __expf(s);
            }
        }
        prevN0 = T << 6;
        if (!hn) break;
        T = Tn; cur ^= 1;
    }
    __syncthreads();
    if (tid < 64) {
        int n = prevN0 + tid;
        if (n < N) {
            float s = sEp[cur][0][tid] + sEp[cur][1][tid]
                    + sEp[cur][2][tid] + sEp[cur][3][tid];
            exo[n] = __expf(s);
        }
    }
}

// ---------------- K7: segment boundaries ----------------
__global__ void k_bounds(const int* __restrict__ seg, int* __restrict__ start, int N, int B) {
    int n = blockIdx.x * blockDim.x + threadIdx.x;
    if (n >= N) return;
    int cur = seg[n];
    int prev = (n == 0) ? -1 : seg[n - 1];
    for (int b = prev + 1; b <= cur; ++b) start[b] = n;
    if (n == N - 1)
        for (int b = cur + 1; b <= B; ++b) start[b] = N;
}

// ---------------- K8: per-segment weighted sum (one wave per segment) ----------------
// rst[b][d] = scale[d] * (sum ex_n * feat_bf16[n][d]) / (sum ex_n) + shift[d]
__global__ __launch_bounds__(256) void k_wsum(const unsigned short* __restrict__ featb,
                                              const int* __restrict__ iid,
                                              const float* __restrict__ exv,
                                              const int* __restrict__ start,
                                              const float* __restrict__ scale,
                                              const float* __restrict__ shift,
                                              float* __restrict__ rst, int B) {
    int tid = threadIdx.x;
    int wv = tid >> 6, lane = tid & 63;
    int b = blockIdx.x * 4 + wv;
    if (b >= B) return;
    int s = start[b], t = start[b + 1];
    float a0 = 0.f, a1 = 0.f, dl = 0.f;
    int voff = lane * 2;     // ushort offset; dword-aligned

    for (int base = s; base < t; base += 64) {
        int idx = base + lane;
        bool valid = (idx < t);
        float e = valid ? exv[idx] : 0.f;
        int   r = valid ? iid[idx] : 0;
        dl += e;
        for (int k = 0; k < 64; k += 4) {
            if (base + k >= t) break;
#pragma unroll
            for (int kk = 0; kk < 4; ++kk) {
                int   rk = __builtin_amdgcn_readlane(r, k + kk);
                float ek = __int_as_float(__builtin_amdgcn_readlane(__float_as_int(e), k + kk));
                unsigned u = *(const unsigned*)(featb + (size_t)rk * 128 + voff);
                a0 += ek * __uint_as_float(u << 16);
                a1 += ek * __uint_as_float(u & 0xffff0000u);
            }
        }
    }
#pragma unroll
    for (int off = 1; off < 64; off <<= 1) dl += __shfl_xor(dl, off);
    float inv = (t > s) ? 1.f / dl : 0.f;
    float msk = (t > s) ? 1.f : 0.f;
    int d0 = lane * 2;
    float r0 = scale[d0] * a0 * inv + shift[d0] * msk;
    float r1 = scale[d0 + 1] * a1 * inv + shift[d0 + 1] * msk;
    *(float2*)&rst[((size_t)b << 7) + d0] = make_float2(r0, r1);
}

// ---------------- K9: out = rst @ W_out  [B,128]x[128,256] ----------------
__global__ __launch_bounds__(256) void k_out(const float* __restrict__ rst, const float* __restrict__ Wout,
                                             float* __restrict__ out, int B) {
    __shared__ float sT[128][36];
    int b0 = blockIdx.x * 32;
    int t = threadIdx.x;
    for (int i = 0; i < 16; ++i) {
        int idx = i * 256 + t;
        int r = idx >> 7, d = idx & 127;
        int b = min(b0 + r, B - 1);
        sT[d][r] = rst[((size_t)b << 7) + d];
    }
    __syncthreads();
    float acc[32];
#pragma unroll
    for (int r = 0; r < 32; ++r) acc[r] = 0.f;
    for (int dd = 0; dd < 128; ++dd) {
        float w = Wout[dd * 256 + t];
        const float4* row = (const float4*)&sT[dd][0];
#pragma unroll
        for (int r4 = 0; r4 < 8; ++r4) {
            float4 v = row[r4];
            acc[r4 * 4 + 0] += w * v.x;
            acc[r4 * 4 + 1] += w * v.y;
            acc[r4 * 4 + 2] += w * v.z;
            acc[r4 * 4 + 3] += w * v.w;
        }
    }
    for (int r = 0; r < 32; ++r)
        if (b0 + r < B) out[(size_t)(b0 + r) * 256 + t] = acc[r];
}

extern "C" void kernel_launch(void* const* d_in, const int* in_sizes, int n_in,
                              void* d_out, int out_size, void* d_ws, size_t ws_size,
                              hipStream_t stream) {
    const float* feat  = (const float*)d_in[0];
    const int*   iid   = (const int*)d_in[1];
    const int*   seg   = (const int*)d_in[2];
    const int*   last  = (const int*)d_in[3];
    const float* gamma = (const float*)d_in[4];
    const float* beta  = (const float*)d_in[5];
    const float* Wu    = (const float*)d_in[6];
    const float* Wv    = (const float*)d_in[7];
    const float* bv    = (const float*)d_in[8];
    const float* we    = (const float*)d_in[9];
    const float* Wout  = (const float*)d_in[10];
    float* out = (float*)d_out;

    int V = in_sizes[0] / 128;
    int N = in_sizes[1];
    int B = in_sizes[3];

    char* w = (char*)d_ws;
    size_t off = 0;
    auto alloc = [&](size_t bytes) -> void* {
        void* p = w + off;
        off += (bytes + 255) & ~(size_t)255;
        return p;
    };
    // zero-init region
    int*   counts = (int*)alloc((size_t)V * 4);
    float* dsum   = (float*)alloc(512);
    float* dsumsq = (float*)alloc(512);
    size_t zero_bytes = off;
    // rest
    float* scale  = (float*)alloc(512);
    float* shift  = (float*)alloc(512);
    float* cbias  = (float*)alloc(512);
    unsigned short* wut = (unsigned short*)alloc(128 * 128 * 2);
    float* wvs    = (float*)alloc(128 * 128 * 4);
    float* fv     = (float*)alloc((size_t)B * 128 * 4);
    unsigned short* featb = (unsigned short*)alloc((size_t)V * 128 * 2);
    float* exo    = (float*)alloc((size_t)N * 4);
    int*   startA = (int*)alloc((size_t)(B + 1) * 4);
    float* rst    = (float*)alloc((size_t)B * 128 * 4);
    (void)ws_size; (void)n_in; (void)out_size;

    hipMemsetAsync(d_ws, 0, zero_bytes, stream);

    k_hist<<<(N + 255) / 256, 256, 0, stream>>>(iid, counts, N);
    k_cvtstats<<<1024, 256, 0, stream>>>(feat, counts, featb, dsum, dsumsq, V);
    k_affine<<<1, 128, 0, stream>>>(dsum, dsumsq, gamma, beta, scale, shift, 1.0f / (float)N);
    k_prep<<<128, 128, 0, stream>>>(Wu, Wv, bv, scale, shift, wut, wvs, cbias);
    k_fv<<<(B + 7) / 8, 128, 0, stream>>>(feat, iid, last, wvs, cbias, fv, B);
    k_bounds<<<(N + 255) / 256, 256, 0, stream>>>(seg, startA, N, B);

    int numTiles = (N + 63) / 64;
    k_main<<<768, 256, 0, stream>>>(featb, iid, seg, wut, fv, we, exo, N, B, numTiles);

    k_wsum<<<(B + 3) / 4, 256, 0, stream>>>(featb, iid, exo, startA, scale, shift, rst, B);
    k_out<<<(B + 31) / 32, 256, 0, stream>>>(rst, Wout, out, B);
}